// Round 4
// baseline (254.153 us; speedup 1.0000x reference)
//
#include <hip/hip_runtime.h>

#define N_NODES 50000
#define N_EDGES 800000
#define D_IN 128
#define HIDDEN 64
#define N_CLASSES 2
#define NB 196          // scan blocks: 196*256 = 50176 >= N_NODES
#define NPAD 50176

// ---------------- degree count (int), 4 edges/thread ----------------

__global__ __launch_bounds__(256) void k_count_deg(const int4* __restrict__ dst4, int* degc) {
    int t = blockIdx.x * 256 + threadIdx.x;
    if (t < N_EDGES / 4) {
        int4 d = dst4[t];
        atomicAdd(&degc[d.x], 1);
        atomicAdd(&degc[d.y], 1);
        atomicAdd(&degc[d.z], 1);
        atomicAdd(&degc[d.w], 1);
    }
}

// ---------------- parallel scan, phase 1: per-block sums ----------------

__global__ __launch_bounds__(256) void k_bsum(const int* __restrict__ degc, int* __restrict__ bsum) {
    __shared__ int part[256];
    int t = threadIdx.x;
    int i = blockIdx.x * 256 + t;
    part[t] = (i < N_NODES) ? degc[i] : 0;
    __syncthreads();
#pragma unroll
    for (int off = 128; off > 0; off >>= 1) {
        if (t < off) part[t] += part[t + off];
        __syncthreads();
    }
    if (t == 0) bsum[blockIdx.x] = part[0];
}

// ---------------- phase 2: scan the 196 block sums (one tiny block) ----------------

__global__ __launch_bounds__(256) void k_scan_bsums(const int* __restrict__ bsum,
                                                    int* __restrict__ boff,
                                                    int* __restrict__ row_ptr) {
    __shared__ int part[256];
    int t = threadIdx.x;
    part[t] = (t < NB) ? bsum[t] : 0;
    __syncthreads();
    for (int off = 1; off < 256; off <<= 1) {
        int v = (t >= off) ? part[t - off] : 0;
        __syncthreads();
        part[t] += v;
        __syncthreads();
    }
    if (t < NB) boff[t] = (t == 0) ? 0 : part[t - 1];
    if (t == 0) row_ptr[N_NODES] = part[NB - 1];  // total == N_EDGES
}

// ---------------- phase 3: per-block exclusive scan + offset (+ dinv fused) ----------------

__global__ __launch_bounds__(256) void k_scan_final(const int* __restrict__ degc,
                                                    const int* __restrict__ boff,
                                                    int* __restrict__ row_ptr,
                                                    int* __restrict__ cursor,
                                                    float* __restrict__ dinv) {
    __shared__ int part[256];
    int t = threadIdx.x;
    int i = blockIdx.x * 256 + t;
    int v = (i < N_NODES) ? degc[i] : 0;
    part[t] = v;
    __syncthreads();
    for (int off = 1; off < 256; off <<= 1) {
        int p = (t >= off) ? part[t - off] : 0;
        __syncthreads();
        part[t] += p;
        __syncthreads();
    }
    if (i < N_NODES) {
        int val = boff[blockIdx.x] + part[t] - v;  // exclusive
        row_ptr[i] = val;
        cursor[i] = val;
        dinv[i] = rsqrtf((float)(v + 1));  // +1 self-loop
    }
}

// ---------------- scatter edges into CSR records (src, w), 4 edges/thread ----------------

__global__ __launch_bounds__(256) void k_scatter(const int4* __restrict__ src4,
                                                 const int4* __restrict__ dst4,
                                                 const float* __restrict__ dinv,
                                                 int* __restrict__ cursor,
                                                 int2* __restrict__ rec) {
    int t = blockIdx.x * 256 + threadIdx.x;
    if (t >= N_EDGES / 4) return;
    int4 s = src4[t];
    int4 d = dst4[t];
    float ws0 = dinv[s.x], ws1 = dinv[s.y], ws2 = dinv[s.z], ws3 = dinv[s.w];
    float wd0 = dinv[d.x], wd1 = dinv[d.y], wd2 = dinv[d.z], wd3 = dinv[d.w];
    int p0 = atomicAdd(&cursor[d.x], 1);
    int p1 = atomicAdd(&cursor[d.y], 1);
    int p2 = atomicAdd(&cursor[d.z], 1);
    int p3 = atomicAdd(&cursor[d.w], 1);
    rec[p0] = make_int2(s.x, __float_as_int(ws0 * wd0));
    rec[p1] = make_int2(s.y, __float_as_int(ws1 * wd1));
    rec[p2] = make_int2(s.z, __float_as_int(ws2 * wd2));
    rec[p3] = make_int2(s.w, __float_as_int(ws3 * wd3));
}

// ---------------- GEMM1: h = x @ W1 ----------------

__device__ inline void fma4(float4& acc, float s, const float4& w) {
    acc.x = fmaf(s, w.x, acc.x);
    acc.y = fmaf(s, w.y, acc.y);
    acc.z = fmaf(s, w.z, acc.z);
    acc.w = fmaf(s, w.w, acc.w);
}

__global__ __launch_bounds__(256) void k_gemm1(
    const float* __restrict__ x, const float* __restrict__ W1, float* __restrict__ h)
{
    __shared__ float Ws[D_IN * HIDDEN];  // [k][col] 32KB
    __shared__ float xs[64 * D_IN];      // [row][k^swz] 32KB
    const int tid = threadIdx.x;
    const int row0 = blockIdx.x * 64;

    const float4* W4 = (const float4*)W1;
    float4* Ws4 = (float4*)Ws;
    for (int i = tid; i < D_IN * HIDDEN / 4; i += 256) Ws4[i] = W4[i];

    for (int i = tid; i < 64 * D_IN / 4; i += 256) {
        int r = i >> 5;
        int k4 = (i & 31) << 2;
        float4 v = make_float4(0.f, 0.f, 0.f, 0.f);
        int grow = row0 + r;
        if (grow < N_NODES) v = *(const float4*)&x[grow * D_IN + k4];
        int sw = ((r >> 2) & 1) << 4;
        *(float4*)&xs[r * D_IN + (k4 ^ sw)] = v;
    }
    __syncthreads();

    const int c4 = (tid & 15) * 4;
    const int r4 = (tid >> 4) * 4;
    float4 acc[4];
#pragma unroll
    for (int j = 0; j < 4; j++) acc[j] = make_float4(0.f, 0.f, 0.f, 0.f);

    for (int k = 0; k < D_IN; k += 4) {
        float4 w0 = *(const float4*)&Ws[(k + 0) * HIDDEN + c4];
        float4 w1 = *(const float4*)&Ws[(k + 1) * HIDDEN + c4];
        float4 w2 = *(const float4*)&Ws[(k + 2) * HIDDEN + c4];
        float4 w3 = *(const float4*)&Ws[(k + 3) * HIDDEN + c4];
        float4 a[4];
#pragma unroll
        for (int j = 0; j < 4; j++) {
            int r = r4 + j;
            int sw = ((r >> 2) & 1) << 4;
            a[j] = *(const float4*)&xs[r * D_IN + (k ^ sw)];
        }
#pragma unroll
        for (int j = 0; j < 4; j++) {
            fma4(acc[j], a[j].x, w0);
            fma4(acc[j], a[j].y, w1);
            fma4(acc[j], a[j].z, w2);
            fma4(acc[j], a[j].w, w3);
        }
    }

#pragma unroll
    for (int j = 0; j < 4; j++) {
        int grow = row0 + r4 + j;
        if (grow < N_NODES) *(float4*)&h[grow * HIDDEN + c4] = acc[j];
    }
}

// ---------------- fused: pull-aggregate layer1 + relu + layer2 + self-loop init ----------------
// one wave per node; lane = feature. Records prefetched 64-wide in ONE coalesced
// load, broadcast via shfl; 4 independent h-row gathers in flight (padded with
// zero-weight edges so the pipeline never drains into a remainder loop).
__global__ __launch_bounds__(256) void k_agg1_l2(
    const float* __restrict__ h, const int* __restrict__ row_ptr,
    const int2* __restrict__ rec, const float* __restrict__ dinv,
    const float* __restrict__ b1, const float* __restrict__ W2,
    const float* __restrict__ b2, float* __restrict__ z, float* __restrict__ out)
{
    int node = blockIdx.x * 4 + (threadIdx.x >> 6);  // grid 12500, exact
    int lane = threadIdx.x & 63;

    float di = dinv[node];
    float acc = h[node * HIDDEN + lane] * (di * di);  // self-loop term

    int beg = row_ptr[node];
    int end = row_ptr[node + 1];

    for (int base = beg; base < end; base += 64) {
        int n = end - base;
        if (n > 64) n = 64;
        int2 r = make_int2(0, 0);  // pad lanes: src=0, w=0 -> harmless fma
        if (lane < n) r = rec[base + lane];
        int n4 = (n + 3) & ~3;
        for (int e = 0; e < n4; e += 4) {
            int   s0 = __shfl(r.x, e + 0, 64);
            float w0 = __int_as_float(__shfl(r.y, e + 0, 64));
            int   s1 = __shfl(r.x, e + 1, 64);
            float w1 = __int_as_float(__shfl(r.y, e + 1, 64));
            int   s2 = __shfl(r.x, e + 2, 64);
            float w2 = __int_as_float(__shfl(r.y, e + 2, 64));
            int   s3 = __shfl(r.x, e + 3, 64);
            float w3 = __int_as_float(__shfl(r.y, e + 3, 64));
            float v0 = h[(size_t)s0 * HIDDEN + lane];
            float v1 = h[(size_t)s1 * HIDDEN + lane];
            float v2 = h[(size_t)s2 * HIDDEN + lane];
            float v3 = h[(size_t)s3 * HIDDEN + lane];
            acc = fmaf(v0, w0, acc);
            acc = fmaf(v1, w1, acc);
            acc = fmaf(v2, w2, acc);
            acc = fmaf(v3, w3, acc);
        }
    }

    // layer 2: y = relu(acc + b1); p = y @ W2 (wave-reduce)
    float y = fmaxf(acc + b1[lane], 0.0f);
    float p0 = y * W2[lane * N_CLASSES + 0];
    float p1 = y * W2[lane * N_CLASSES + 1];
#pragma unroll
    for (int off = 32; off > 0; off >>= 1) {
        p0 += __shfl_down(p0, off, 64);
        p1 += __shfl_down(p1, off, 64);
    }
    if (lane == 0) {
        float s2 = di * di;
        z[node * 2 + 0] = p0;
        z[node * 2 + 1] = p1;
        out[node * 2 + 0] = fmaf(p0, s2, b2[0]);  // self-loop + bias init
        out[node * 2 + 1] = fmaf(p1, s2, b2[1]);
    }
}

// ---------------- pull-aggregate layer 2: wave per node, lane-parallel edges ----------------

__global__ __launch_bounds__(256) void k_agg2(
    const float* __restrict__ z, const int* __restrict__ row_ptr,
    const int2* __restrict__ rec, float* __restrict__ out)
{
    int node = blockIdx.x * 4 + (threadIdx.x >> 6);  // grid 12500, exact
    int lane = threadIdx.x & 63;
    int beg = row_ptr[node];
    int end = row_ptr[node + 1];
    float a0 = 0.f, a1 = 0.f;
    for (int idx = beg + lane; idx < end; idx += 64) {
        int2 r = rec[idx];
        float w = __int_as_float(r.y);
        float2 v = *(const float2*)&z[r.x * 2];
        a0 = fmaf(v.x, w, a0);
        a1 = fmaf(v.y, w, a1);
    }
#pragma unroll
    for (int off = 32; off > 0; off >>= 1) {
        a0 += __shfl_down(a0, off, 64);
        a1 += __shfl_down(a1, off, 64);
    }
    if (lane == 0) {
        out[node * 2 + 0] += a0;  // out pre-initialized with self-loop + bias
        out[node * 2 + 1] += a1;
    }
}

// ---------------- launch ----------------

extern "C" void kernel_launch(void* const* d_in, const int* in_sizes, int n_in,
                              void* d_out, int out_size, void* d_ws, size_t ws_size,
                              hipStream_t stream) {
    const float* x  = (const float*)d_in[0];
    const int* ei   = (const int*)d_in[1];
    const float* W1 = (const float*)d_in[2];
    const float* b1 = (const float*)d_in[3];
    const float* W2 = (const float*)d_in[4];
    const float* b2 = (const float*)d_in[5];
    float* out = (float*)d_out;

    const int* src = ei;
    const int* dst = ei + N_EDGES;

    // workspace layout (4-byte units)
    int*   degc    = (int*)d_ws;                     // [0, 50176)
    float* dinv    = (float*)d_ws + NPAD;            // [50176, 100352)
    int*   row_ptr = (int*)d_ws + 2 * NPAD;          // 50001 -> pad to 150532
    int*   cursor  = (int*)d_ws + 150532;            // [150532, 200708)
    int*   bsum    = (int*)d_ws + 200708;            // 196 -> pad to 200964
    int*   boff    = (int*)d_ws + 200964;            // 196 -> pad to 201220 (16B-aligned)
    int2*  rec     = (int2*)((int*)d_ws + 201220);   // 800000 int2 = 1.6M units
    float* h       = (float*)d_ws + 1801220;         // 3.2M units (16B aligned)
    float* z       = (float*)d_ws + 5001220;         // 100k units

    hipMemsetAsync(degc, 0, NPAD * sizeof(int), stream);
    k_count_deg<<<(N_EDGES / 4 + 255) / 256, 256, 0, stream>>>((const int4*)dst, degc);
    k_bsum<<<NB, 256, 0, stream>>>(degc, bsum);
    k_scan_bsums<<<1, 256, 0, stream>>>(bsum, boff, row_ptr);
    k_scan_final<<<NB, 256, 0, stream>>>(degc, boff, row_ptr, cursor, dinv);
    k_scatter<<<(N_EDGES / 4 + 255) / 256, 256, 0, stream>>>((const int4*)src, (const int4*)dst, dinv, cursor, rec);
    k_gemm1<<<(N_NODES + 63) / 64, 256, 0, stream>>>(x, W1, h);
    k_agg1_l2<<<N_NODES / 4, 256, 0, stream>>>(h, row_ptr, rec, dinv, b1, W2, b2, z, out);
    k_agg2<<<N_NODES / 4, 256, 0, stream>>>(z, row_ptr, rec, out);
}